// Round 2
// baseline (379.296 us; speedup 1.0000x reference)
//
#include <hip/hip_runtime.h>
#include <math.h>

#define BETA  0.125f    // 1/sqrt(64)
#define SHIFT 30.0f     // fixed softmax shift; logits = beta*cosh(d) in [0.125, 68.5]
#define EPSF  1e-7f
#define EPSD  1e-7

// ---------------------------------------------------------------------------
// Projection (+optional second projection) + expmap0 epilogue.
// X: rows x 256 (row-major), W: 64 x 256, bias: 64.
// DOUBLE: apply W2 (64x64), b2 afterwards (for V path).
// Outputs: y0[row] = cosh(theta), yr[row][64] = sinh(theta)*x*factor/xn.
// ---------------------------------------------------------------------------
template <bool DOUBLE>
__global__ __launch_bounds__(256) void proj_expmap_kernel(
    const float* __restrict__ X, const float* __restrict__ W,
    const float* __restrict__ bias, const float* __restrict__ W2,
    const float* __restrict__ b2, float* __restrict__ y0,
    float* __restrict__ yr)
{
  __shared__ float Xs[64][68];
  __shared__ float Ws_[64][68];
  __shared__ float Cs[64][68];
  __shared__ float scaleS[64];

  const int tid = threadIdx.x;
  const int ty = tid >> 4, tx = tid & 15;
  const int ty4 = ty << 2, tx4 = tx << 2;
  const int rowBase = blockIdx.x * 64;

  float acc[4][4];
#pragma unroll
  for (int j = 0; j < 4; ++j) {
    float bj = bias[tx4 + j];
#pragma unroll
    for (int i = 0; i < 4; ++i) acc[i][j] = bj;
  }

  for (int kc = 0; kc < 4; ++kc) {
#pragma unroll
    for (int q = 0; q < 4; ++q) {
      int f = tid + 256 * q;
      int r = f >> 4, c4 = (f & 15) << 2;
      *(float4*)&Xs[r][c4]  = *(const float4*)&X[(rowBase + r) * 256 + kc * 64 + c4];
      *(float4*)&Ws_[r][c4] = *(const float4*)&W[r * 256 + kc * 64 + c4];
    }
    __syncthreads();
#pragma unroll 4
    for (int kk = 0; kk < 64; kk += 4) {
      float4 xa[4], wb[4];
#pragma unroll
      for (int i = 0; i < 4; ++i) xa[i] = *(const float4*)&Xs[ty4 + i][kk];
#pragma unroll
      for (int j = 0; j < 4; ++j) wb[j] = *(const float4*)&Ws_[tx4 + j][kk];
#pragma unroll
      for (int i = 0; i < 4; ++i)
#pragma unroll
        for (int j = 0; j < 4; ++j)
          acc[i][j] += xa[i].x * wb[j].x + xa[i].y * wb[j].y +
                       xa[i].z * wb[j].z + xa[i].w * wb[j].w;
    }
    __syncthreads();
  }

#pragma unroll
  for (int i = 0; i < 4; ++i)
#pragma unroll
    for (int j = 0; j < 4; ++j) Cs[ty4 + i][tx4 + j] = acc[i][j];
  __syncthreads();

  if (DOUBLE) {
#pragma unroll
    for (int q = 0; q < 4; ++q) {
      int f = tid + 256 * q;
      int r = f >> 4, c4 = (f & 15) << 2;
      *(float4*)&Ws_[r][c4] = *(const float4*)&W2[r * 64 + c4];
    }
    __syncthreads();
    float acc2[4][4];
#pragma unroll
    for (int j = 0; j < 4; ++j) {
      float bj = b2[tx4 + j];
#pragma unroll
      for (int i = 0; i < 4; ++i) acc2[i][j] = bj;
    }
#pragma unroll 4
    for (int kk = 0; kk < 64; kk += 4) {
      float4 xa[4], wb[4];
#pragma unroll
      for (int i = 0; i < 4; ++i) xa[i] = *(const float4*)&Cs[ty4 + i][kk];
#pragma unroll
      for (int j = 0; j < 4; ++j) wb[j] = *(const float4*)&Ws_[tx4 + j][kk];
#pragma unroll
      for (int i = 0; i < 4; ++i)
#pragma unroll
        for (int j = 0; j < 4; ++j)
          acc2[i][j] += xa[i].x * wb[j].x + xa[i].y * wb[j].y +
                        xa[i].z * wb[j].z + xa[i].w * wb[j].w;
    }
    __syncthreads();
#pragma unroll
    for (int i = 0; i < 4; ++i)
#pragma unroll
      for (int j = 0; j < 4; ++j) Cs[ty4 + i][tx4 + j] = acc2[i][j];
    __syncthreads();
  }

  // expmap0 epilogue (one thread per row)
  if (tid < 64) {
    float n2 = 0.f;
    for (int j = 0; j < 64; ++j) {
      float v = Cs[tid][j];
      n2 += v * v;
    }
    float n = sqrtf(n2);
    float factor = fminf(3.5f / (n + EPSF), 1.0f);
    float xn = fmaxf(n * factor, EPSF);
    float sh = sinhf(xn), ch = coshf(xn);
    scaleS[tid] = sh * factor / xn;
    y0[rowBase + tid] = ch;
  }
  __syncthreads();
#pragma unroll
  for (int q = 0; q < 4; ++q) {
    int f = tid + 256 * q;
    int r = f >> 4, c4 = (f & 15) << 2;
    float sc = scaleS[r];
    float4 v = *(const float4*)&Cs[r][c4];
    v.x *= sc; v.y *= sc; v.z *= sc; v.w *= sc;
    *(float4*)&yr[(rowBase + r) * 64 + c4] = v;
  }
}

// ---------------------------------------------------------------------------
// Attention core: per WG 64 s-rows x 1024 m-slice (16 chunks of 64).
// Fixed-shift exp (logits bounded). On-hyperboloid identities hardwired:
// qq = vv = -1  =>  nomin = c^2 - 1, denom = sinh(dist).
// Writes unnormalized partials T[d], T0, L, WC per (slice,b,s).
// ---------------------------------------------------------------------------
__global__ __launch_bounds__(256, 2) void attn_kernel(
    const float* __restrict__ Q0, const float* __restrict__ Qr,
    const float* __restrict__ K0, const float* __restrict__ Kr,
    const float* __restrict__ V0, const float* __restrict__ Vr,
    float* __restrict__ Tpart, float* __restrict__ T0part,
    float* __restrict__ Lpart, float* __restrict__ WCpart)
{
  __shared__ float Qs[64][68];
  __shared__ float Ks[64][68];
  __shared__ float Vs[64][68];
  __shared__ float Wt[64][68];
  __shared__ float Q0s[64], K0s[64], V0s[64];

  const int tid = threadIdx.x;
  const int ty = tid >> 4, tx = tid & 15;
  const int ty4 = ty << 2, tx4 = tx << 2;
  const int b = blockIdx.z;
  const int sBase = blockIdx.x * 64;
  const int rowQ = (b << 11) + sBase;

#pragma unroll
  for (int q = 0; q < 4; ++q) {
    int f = tid + 256 * q;
    int r = f >> 4, c4 = (f & 15) << 2;
    *(float4*)&Qs[r][c4] = *(const float4*)&Qr[(rowQ + r) * 64 + c4];
  }
  if (tid < 64) Q0s[tid] = Q0[rowQ + tid];

  float accT[4][4], Lp[4], WCp[4], T0p[4];
#pragma unroll
  for (int i = 0; i < 4; ++i) {
    Lp[i] = 0.f; WCp[i] = 0.f; T0p[i] = 0.f;
#pragma unroll
    for (int j = 0; j < 4; ++j) accT[i][j] = 0.f;
  }
  __syncthreads();

  const int mBase = (b << 12) + blockIdx.y * 1024;
  for (int mc = 0; mc < 16; ++mc) {
    const int mG = mBase + mc * 64;
#pragma unroll
    for (int q = 0; q < 4; ++q) {
      int f = tid + 256 * q;
      int r = f >> 4, c4 = (f & 15) << 2;
      *(float4*)&Ks[r][c4] = *(const float4*)&Kr[(mG + r) * 64 + c4];
      *(float4*)&Vs[r][c4] = *(const float4*)&Vr[(mG + r) * 64 + c4];
    }
    if (tid < 64) {
      K0s[tid] = K0[mG + tid];
      V0s[tid] = V0[mG + tid];
    }
    __syncthreads();

    // Phase A: dual Minkowski dots (sims with K, ip with V)
    float sims[4][4], ipv[4][4];
#pragma unroll
    for (int i = 0; i < 4; ++i) {
      float q0i = Q0s[ty4 + i];
#pragma unroll
      for (int j = 0; j < 4; ++j) {
        sims[i][j] = -q0i * K0s[tx4 + j];
        ipv[i][j]  = -q0i * V0s[tx4 + j];
      }
    }
#pragma unroll 4
    for (int kk = 0; kk < 64; kk += 4) {
      float4 qa[4], ka[4], va[4];
#pragma unroll
      for (int i = 0; i < 4; ++i) qa[i] = *(const float4*)&Qs[ty4 + i][kk];
#pragma unroll
      for (int j = 0; j < 4; ++j) {
        ka[j] = *(const float4*)&Ks[tx4 + j][kk];
        va[j] = *(const float4*)&Vs[tx4 + j][kk];
      }
#pragma unroll
      for (int i = 0; i < 4; ++i)
#pragma unroll
        for (int j = 0; j < 4; ++j) {
          sims[i][j] += qa[i].x * ka[j].x + qa[i].y * ka[j].y +
                        qa[i].z * ka[j].z + qa[i].w * ka[j].w;
          ipv[i][j]  += qa[i].x * va[j].x + qa[i].y * va[j].y +
                        qa[i].z * va[j].z + qa[i].w * va[j].w;
        }
    }

    // elementwise weights: w = e * acosh(-c) / sqrt(c^2-1)
#pragma unroll
    for (int i = 0; i < 4; ++i) {
#pragma unroll
      for (int j = 0; j < 4; ++j) {
        float c = ipv[i][j];
        float e = __expf(fmaf(-BETA, sims[i][j], -SHIFT));
        float dist = acoshf(fmaxf(-c, 1.0f + EPSF));
        float denom = sqrtf(fmaxf(c * c - 1.0f, EPSF));
        float w = e * dist / denom;
        Wt[ty4 + i][tx4 + j] = w;
        Lp[i]  += e;
        WCp[i] += w * c;
        T0p[i] += w * V0s[tx4 + j];
      }
    }
    __syncthreads();

    // Phase B: T[s][d] += W[s][m] * Vr[m][d]
#pragma unroll 4
    for (int mm = 0; mm < 64; mm += 4) {
      float4 wa[4];
      float vb[4][4];
#pragma unroll
      for (int i = 0; i < 4; ++i) wa[i] = *(const float4*)&Wt[ty4 + i][mm];
#pragma unroll
      for (int qd = 0; qd < 4; ++qd) {
        float4 t = *(const float4*)&Vs[mm + qd][tx4];
        vb[qd][0] = t.x; vb[qd][1] = t.y; vb[qd][2] = t.z; vb[qd][3] = t.w;
      }
#pragma unroll
      for (int i = 0; i < 4; ++i)
#pragma unroll
        for (int j = 0; j < 4; ++j)
          accT[i][j] += wa[i].x * vb[0][j] + wa[i].y * vb[1][j] +
                        wa[i].z * vb[2][j] + wa[i].w * vb[3][j];
    }
    __syncthreads();
  }

  // reduce row-scalars over the 16 tx lanes (lane bits 0..3 == tx)
#pragma unroll
  for (int i = 0; i < 4; ++i) {
#pragma unroll
    for (int off = 1; off < 16; off <<= 1) {
      Lp[i]  += __shfl_xor(Lp[i], off);
      WCp[i] += __shfl_xor(WCp[i], off);
      T0p[i] += __shfl_xor(T0p[i], off);
    }
  }

  const int rowP = ((blockIdx.y * 2 + b) << 11) + sBase;
#pragma unroll
  for (int i = 0; i < 4; ++i) {
    float4 v = make_float4(accT[i][0], accT[i][1], accT[i][2], accT[i][3]);
    *(float4*)&Tpart[(rowP + ty4 + i) * 64 + tx4] = v;
    if (tx == 0) {
      T0part[rowP + ty4 + i] = T0p[i];
      Lpart[rowP + ty4 + i]  = Lp[i];
      WCpart[rowP + ty4 + i] = WCp[i];
    }
  }
}

// ---------------------------------------------------------------------------
// Combine: one wave per (b,s) row, f64 internally.
// Stability: <tm,tm> = <t,t> + wc^2   (uses <t,Q>=wc, <Q,Q>=-1 identities)
// which avoids the ~1e4x cancellation of computing sum(tmd^2) - tm0^2.
// ---------------------------------------------------------------------------
__global__ __launch_bounds__(256) void combine_kernel(
    const float* __restrict__ Q0, const float* __restrict__ Qr,
    const float* __restrict__ Tpart, const float* __restrict__ T0part,
    const float* __restrict__ Lpart, const float* __restrict__ WCpart,
    float* __restrict__ out)
{
  int wid = (blockIdx.x << 2) + (threadIdx.x >> 6);  // global wave = (b,s) row
  int lane = threadIdx.x & 63;
  int b = wid >> 11;
  int s = wid & 2047;

  double Tsum = 0.0, T0 = 0.0, L = 0.0, WC = 0.0;
#pragma unroll
  for (int sl = 0; sl < 4; ++sl) {
    int rp = ((sl * 2 + b) << 11) + s;
    Tsum += (double)Tpart[rp * 64 + lane];
    T0 += (double)T0part[rp];
    L  += (double)Lpart[rp];
    WC += (double)WCpart[rp];
  }
  double qd = (double)Qr[wid * 64 + lane];
  double q0 = (double)Q0[wid];
  double invL = 1.0 / L;
  double td = Tsum * invL;          // t = T/L (small components, ~0.4)
  double t0 = T0 * invL;
  double wc = WC * invL;

  // <t,t> Minkowski (well-conditioned: components O(0.4))
  double tt = td * td;
#pragma unroll
  for (int off = 1; off < 64; off <<= 1) tt += __shfl_xor(tt, off);
  tt -= t0 * t0;

  double mk = tt + wc * wc;         // <tm,tm> via tangency identity
  double un = sqrt(fmax(mk, EPSD));
  double ch = cosh(un), shu = sinh(un) / un;

  double tmd = td + wc * qd;
  double tm0 = t0 + wc * q0;
  double zd = ch * qd + shu * tmd;
  double z0 = ch * q0 + shu * tm0;

  double p2 = zd * zd;
#pragma unroll
  for (int off = 1; off < 64; off <<= 1) p2 += __shfl_xor(p2, off);
  double yn = fmax(sqrt(p2), EPSD);
  double dl = acosh(fmax(z0, 1.0 + EPSD));
  out[wid * 64 + lane] = (float)(dl * zd / yn);
}

// ---------------------------------------------------------------------------
extern "C" void kernel_launch(void* const* d_in, const int* in_sizes, int n_in,
                              void* d_out, int out_size, void* d_ws, size_t ws_size,
                              hipStream_t stream)
{
  const float* queries = (const float*)d_in[0];
  const float* keys    = (const float*)d_in[1];
  const float* values  = (const float*)d_in[2];
  const float* Wq      = (const float*)d_in[3];
  const float* bq      = (const float*)d_in[4];
  const float* Wk      = (const float*)d_in[5];
  const float* bk      = (const float*)d_in[6];
  const float* Wv      = (const float*)d_in[7];
  const float* bv      = (const float*)d_in[8];
  float* out = (float*)d_out;
  float* ws  = (float*)d_ws;

  // workspace layout (floats)
  float* Q0 = ws;                 // 4096
  float* Qr = ws + 4096;          // 262144
  float* K0 = ws + 266240;        // 8192
  float* Kr = ws + 274432;        // 524288
  float* V0 = ws + 798720;        // 8192
  float* Vr = ws + 806912;        // 524288
  float* Tpart  = ws + 1331200;   // 8*2048*64 = 1048576
  float* T0part = ws + 2379776;   // 16384
  float* Lpart  = ws + 2396160;   // 16384
  float* WCpart = ws + 2412544;   // 16384

  proj_expmap_kernel<false><<<64, 256, 0, stream>>>(
      queries, Wq, bq, nullptr, nullptr, Q0, Qr);
  proj_expmap_kernel<false><<<128, 256, 0, stream>>>(
      keys, Wk, bk, nullptr, nullptr, K0, Kr);
  proj_expmap_kernel<true><<<128, 256, 0, stream>>>(
      values, Wk, bk, Wv, bv, V0, Vr);
  attn_kernel<<<dim3(32, 4, 2), 256, 0, stream>>>(
      Q0, Qr, K0, Kr, V0, Vr, Tpart, T0part, Lpart, WCpart);
  combine_kernel<<<1024, 256, 0, stream>>>(
      Q0, Qr, Tpart, T0part, Lpart, WCpart, out);
}

// Round 3
// 230.438 us; speedup vs baseline: 1.6460x; 1.6460x over previous
//
#include <hip/hip_runtime.h>
#include <math.h>

#define BETA  0.125f    // 1/sqrt(64)
#define SHIFT 30.0f     // fixed softmax shift; logits bounded in [0.125, 68.5]
#define EPSF  1e-7f
#define EPSD  1e-7

// ---------------------------------------------------------------------------
// Merged projection kernel. Blocks 0..63: Q path; 64..191: K path;
// 192..319: V path (double projection). 64x64 output tile per block,
// XOR-swizzled LDS (bank-conflict-free), register-resident expmap epilogue.
// ---------------------------------------------------------------------------
__global__ __launch_bounds__(256) void proj_kernel(
    const float* __restrict__ Xq, const float* __restrict__ Xk,
    const float* __restrict__ Xv,
    const float* __restrict__ Wq, const float* __restrict__ bq,
    const float* __restrict__ Wk, const float* __restrict__ bk,
    const float* __restrict__ Wv, const float* __restrict__ bv,
    float* __restrict__ Q0, float* __restrict__ Qr,
    float* __restrict__ K0, float* __restrict__ Kr,
    float* __restrict__ V0, float* __restrict__ Vr)
{
  __shared__ float Xs[64 * 64];   // swizzled; reused as C-tile for V path
  __shared__ float Ws[64 * 64];   // swizzled

  const int bid = blockIdx.x;
  const float *X, *W, *bias;
  float *y0, *yr;
  bool dbl;
  int rowBase;
  if (bid < 64)       { X = Xq; W = Wq; bias = bq; y0 = Q0; yr = Qr; rowBase = bid << 6;         dbl = false; }
  else if (bid < 192) { X = Xk; W = Wk; bias = bk; y0 = K0; yr = Kr; rowBase = (bid - 64) << 6;  dbl = false; }
  else                { X = Xv; W = Wk; bias = bk; y0 = V0; yr = Vr; rowBase = (bid - 192) << 6; dbl = true;  }

  const int tid = threadIdx.x;
  const int ty = tid >> 4, tx = tid & 15;
  const int ty4 = ty << 2, tx4 = tx << 2;

  float acc[4][4];
#pragma unroll
  for (int j = 0; j < 4; ++j) {
    float bj = bias[tx4 + j];
#pragma unroll
    for (int i = 0; i < 4; ++i) acc[i][j] = bj;
  }

  for (int kc = 0; kc < 4; ++kc) {
#pragma unroll
    for (int q = 0; q < 4; ++q) {
      int f = tid + (q << 8);
      int r = f >> 4, g = f & 15;
      int sw = (r << 6) + ((g ^ (r >> 2)) << 2);
      *(float4*)&Xs[sw] = *(const float4*)&X[(rowBase + r) * 256 + (kc << 6) + (g << 2)];
      *(float4*)&Ws[sw] = *(const float4*)&W[r * 256 + (kc << 6) + (g << 2)];
    }
    __syncthreads();
#pragma unroll 4
    for (int kk = 0; kk < 64; kk += 4) {
      const int gk = kk >> 2;
      float4 xa[4], wb[4];
#pragma unroll
      for (int i = 0; i < 4; ++i)
        xa[i] = *(const float4*)&Xs[((ty4 + i) << 6) + ((gk ^ ty) << 2)];
#pragma unroll
      for (int j = 0; j < 4; ++j)
        wb[j] = *(const float4*)&Ws[((tx4 + j) << 6) + ((gk ^ tx) << 2)];
#pragma unroll
      for (int i = 0; i < 4; ++i)
#pragma unroll
        for (int j = 0; j < 4; ++j)
          acc[i][j] += xa[i].x * wb[j].x + xa[i].y * wb[j].y +
                       xa[i].z * wb[j].z + xa[i].w * wb[j].w;
    }
    __syncthreads();
  }

  if (dbl) {
    // write C tile (swizzled) into Xs, stage W2 into Ws
#pragma unroll
    for (int i = 0; i < 4; ++i) {
      float4 v = make_float4(acc[i][0], acc[i][1], acc[i][2], acc[i][3]);
      *(float4*)&Xs[((ty4 + i) << 6) + ((tx ^ ty) << 2)] = v;
    }
#pragma unroll
    for (int q = 0; q < 4; ++q) {
      int f = tid + (q << 8);
      int r = f >> 4, g = f & 15;
      int sw = (r << 6) + ((g ^ (r >> 2)) << 2);
      *(float4*)&Ws[sw] = *(const float4*)&Wv[(r << 6) + (g << 2)];
    }
#pragma unroll
    for (int j = 0; j < 4; ++j) {
      float bj = bv[tx4 + j];
#pragma unroll
      for (int i = 0; i < 4; ++i) acc[i][j] = bj;  // re-init for GEMM2
    }
    __syncthreads();
#pragma unroll 4
    for (int kk = 0; kk < 64; kk += 4) {
      const int gk = kk >> 2;
      float4 xa[4], wb[4];
#pragma unroll
      for (int i = 0; i < 4; ++i)
        xa[i] = *(const float4*)&Xs[((ty4 + i) << 6) + ((gk ^ ty) << 2)];
#pragma unroll
      for (int j = 0; j < 4; ++j)
        wb[j] = *(const float4*)&Ws[((tx4 + j) << 6) + ((gk ^ tx) << 2)];
#pragma unroll
      for (int i = 0; i < 4; ++i)
#pragma unroll
        for (int j = 0; j < 4; ++j)
          acc[i][j] += xa[i].x * wb[j].x + xa[i].y * wb[j].y +
                       xa[i].z * wb[j].z + xa[i].w * wb[j].w;
    }
  }

  // expmap0 epilogue, fully in registers + shuffles (tx = lane&15)
  float n2p[4];
#pragma unroll
  for (int i = 0; i < 4; ++i)
    n2p[i] = acc[i][0] * acc[i][0] + acc[i][1] * acc[i][1] +
             acc[i][2] * acc[i][2] + acc[i][3] * acc[i][3];
#pragma unroll
  for (int i = 0; i < 4; ++i) {
    n2p[i] += __shfl_xor(n2p[i], 1);
    n2p[i] += __shfl_xor(n2p[i], 2);
    n2p[i] += __shfl_xor(n2p[i], 4);
    n2p[i] += __shfl_xor(n2p[i], 8);
  }
#pragma unroll
  for (int i = 0; i < 4; ++i) {
    float n = sqrtf(n2p[i]);
    float factor = fminf(3.5f / (n + EPSF), 1.0f);
    float xn = fmaxf(n * factor, EPSF);
    float et = __expf(xn);
    float rt = __builtin_amdgcn_rcpf(et);
    float ch = 0.5f * (et + rt);
    float sh = 0.5f * (et - rt);
    float scale = sh * factor * __builtin_amdgcn_rcpf(xn);
    if (tx == 0) y0[rowBase + ty4 + i] = ch;
    float4 v = make_float4(acc[i][0] * scale, acc[i][1] * scale,
                           acc[i][2] * scale, acc[i][3] * scale);
    *(float4*)&yr[(rowBase + ty4 + i) * 64 + tx4] = v;
  }
}

// ---------------------------------------------------------------------------
// Attention core. Grid (32 s-tiles, SL m-slices, 2 batches). Per WG: 64 s-rows
// x nChunk chunks of 64 m. XOR-swizzled K/V LDS (conflict-free Phase A);
// weight tile overlays Ks after Phase A (LDS ~49 KB -> 3 WGs/CU).
// Hardwired hyperboloid identities: nomin = c^2-1 => w = e*acosh(-c)*rsq(c^2-1).
// ---------------------------------------------------------------------------
__global__ __launch_bounds__(256, 3) void attn_kernel(
    const float* __restrict__ Q0g, const float* __restrict__ Qrg,
    const float* __restrict__ K0g, const float* __restrict__ Krg,
    const float* __restrict__ V0g, const float* __restrict__ Vrg,
    float* __restrict__ Tpart, float* __restrict__ T0part,
    float* __restrict__ Lpart, float* __restrict__ WCpart, int nChunk)
{
  __shared__ float Qs[64 * 64];   // plain layout (broadcast reads)
  __shared__ float Ks[64 * 64];   // swizzled; overlaid by weight tile in Phase B
  __shared__ float Vs[64 * 64];   // swizzled
  __shared__ float Q0s[64], K0s[64], V0s[64];

  const int tid = threadIdx.x;
  const int ty = tid >> 4, tx = tid & 15;
  const int ty4 = ty << 2, tx4 = tx << 2;
  const int b = blockIdx.z;
  const int sl = blockIdx.y;
  const int rowQ = (b << 11) + (blockIdx.x << 6);

#pragma unroll
  for (int q = 0; q < 4; ++q) {
    int f = tid + (q << 8);
    int r = f >> 4, g = f & 15;
    *(float4*)&Qs[(r << 6) + (g << 2)] =
        *(const float4*)&Qrg[(rowQ + r) * 64 + (g << 2)];
  }
  if (tid < 64) Q0s[tid] = Q0g[rowQ + tid];

  float accT[4][4], Lp[4], WCp[4], T0p[4];
#pragma unroll
  for (int i = 0; i < 4; ++i) {
    Lp[i] = 0.f; WCp[i] = 0.f; T0p[i] = 0.f;
#pragma unroll
    for (int j = 0; j < 4; ++j) accT[i][j] = 0.f;
  }
  __syncthreads();

  const int mStart = (b << 12) + sl * (nChunk << 6);
  for (int mc = 0; mc < nChunk; ++mc) {
    const int mG = mStart + (mc << 6);
#pragma unroll
    for (int q = 0; q < 4; ++q) {
      int f = tid + (q << 8);
      int r = f >> 4, g = f & 15;
      int sw = (r << 6) + ((g ^ (r >> 2)) << 2);
      *(float4*)&Ks[sw] = *(const float4*)&Krg[(mG + r) * 64 + (g << 2)];
      *(float4*)&Vs[sw] = *(const float4*)&Vrg[(mG + r) * 64 + (g << 2)];
    }
    if (tid < 64) {
      K0s[tid] = K0g[mG + tid];
      V0s[tid] = V0g[mG + tid];
    }
    __syncthreads();

    // Phase A: dual Minkowski dots (sims with K, ip with V)
    float sims[4][4], ipv[4][4];
#pragma unroll
    for (int i = 0; i < 4; ++i) {
      float q0i = Q0s[ty4 + i];
#pragma unroll
      for (int j = 0; j < 4; ++j) {
        sims[i][j] = -q0i * K0s[tx4 + j];
        ipv[i][j]  = -q0i * V0s[tx4 + j];
      }
    }
#pragma unroll 4
    for (int kk = 0; kk < 64; kk += 4) {
      const int gsw = ((kk >> 2) ^ tx) << 2;
      float4 qa[4], ka[4], va[4];
#pragma unroll
      for (int i = 0; i < 4; ++i)
        qa[i] = *(const float4*)&Qs[((ty4 + i) << 6) + kk];
#pragma unroll
      for (int j = 0; j < 4; ++j) {
        int base = ((tx4 + j) << 6) + gsw;
        ka[j] = *(const float4*)&Ks[base];
        va[j] = *(const float4*)&Vs[base];
      }
#pragma unroll
      for (int i = 0; i < 4; ++i)
#pragma unroll
        for (int j = 0; j < 4; ++j) {
          sims[i][j] += qa[i].x * ka[j].x + qa[i].y * ka[j].y +
                        qa[i].z * ka[j].z + qa[i].w * ka[j].w;
          ipv[i][j]  += qa[i].x * va[j].x + qa[i].y * va[j].y +
                        qa[i].z * va[j].z + qa[i].w * va[j].w;
        }
    }
    __syncthreads();  // Ks fully consumed; safe to overlay weight tile

    // elementwise: w = e * acosh(-c) / sqrt(c^2-1); rsq shared
#pragma unroll
    for (int i = 0; i < 4; ++i) {
#pragma unroll
      for (int j = 0; j < 4; ++j) {
        float c = ipv[i][j];
        float x = -c;
        float s2 = fmaxf(fmaf(x, x, -1.0f), EPSF);
        float rs = __builtin_amdgcn_rsqf(s2);
        float dist = __logf(fmaf(s2, rs, x));   // log(x + sqrt(x^2-1))
        float e = __expf(fmaf(-BETA, sims[i][j], -SHIFT));
        float w = e * dist * rs;
        Ks[((ty4 + i) << 6) + ((tx ^ ty) << 2) + j] = w;  // swizzled Wt
        Lp[i]  += e;
        WCp[i] += w * c;
        T0p[i] += w * V0s[tx4 + j];
      }
    }
    __syncthreads();

    // Phase B: T[s][d] += W[s][m] * Vr[m][d]
#pragma unroll 4
    for (int mm = 0; mm < 64; mm += 4) {
      float4 wa[4];
      float vb[4][4];
#pragma unroll
      for (int i = 0; i < 4; ++i)
        wa[i] = *(const float4*)&Ks[((ty4 + i) << 6) + ((((mm >> 2) ^ ty)) << 2)];
#pragma unroll
      for (int qd = 0; qd < 4; ++qd) {
        int rr = mm + qd;
        float4 t = *(const float4*)&Vs[(rr << 6) + ((tx ^ (rr >> 2)) << 2)];
        vb[qd][0] = t.x; vb[qd][1] = t.y; vb[qd][2] = t.z; vb[qd][3] = t.w;
      }
#pragma unroll
      for (int i = 0; i < 4; ++i)
#pragma unroll
        for (int j = 0; j < 4; ++j)
          accT[i][j] += wa[i].x * vb[0][j] + wa[i].y * vb[1][j] +
                        wa[i].z * vb[2][j] + wa[i].w * vb[3][j];
    }
    __syncthreads();
  }

  // reduce row-scalars over the 16 tx lanes
#pragma unroll
  for (int i = 0; i < 4; ++i) {
#pragma unroll
    for (int off = 1; off < 16; off <<= 1) {
      Lp[i]  += __shfl_xor(Lp[i], off);
      WCp[i] += __shfl_xor(WCp[i], off);
      T0p[i] += __shfl_xor(T0p[i], off);
    }
  }

  const int rowP = (sl << 12) + rowQ;
#pragma unroll
  for (int i = 0; i < 4; ++i) {
    float4 v = make_float4(accT[i][0], accT[i][1], accT[i][2], accT[i][3]);
    *(float4*)&Tpart[(rowP + ty4 + i) * 64 + tx4] = v;
    if (tx == 0) {
      T0part[rowP + ty4 + i] = T0p[i];
      Lpart[rowP + ty4 + i]  = Lp[i];
      WCpart[rowP + ty4 + i] = WCp[i];
    }
  }
}

// ---------------------------------------------------------------------------
// Combine: one wave per (b,s) row, f64 internally.
// <tm,tm> = <t,t> + wc^2  (tangency identity; avoids 1e4x cancellation).
// ---------------------------------------------------------------------------
__global__ __launch_bounds__(256) void combine_kernel(
    const float* __restrict__ Q0, const float* __restrict__ Qr,
    const float* __restrict__ Tpart, const float* __restrict__ T0part,
    const float* __restrict__ Lpart, const float* __restrict__ WCpart,
    float* __restrict__ out, int nSl)
{
  int wid = (blockIdx.x << 2) + (threadIdx.x >> 6);  // global (b,s) row
  int lane = threadIdx.x & 63;

  double Tsum = 0.0, T0 = 0.0, L = 0.0, WC = 0.0;
  for (int sli = 0; sli < nSl; ++sli) {
    int rp = (sli << 12) + wid;
    Tsum += (double)Tpart[rp * 64 + lane];
    T0 += (double)T0part[rp];
    L  += (double)Lpart[rp];
    WC += (double)WCpart[rp];
  }
  double qd = (double)Qr[wid * 64 + lane];
  double q0 = (double)Q0[wid];
  double invL = 1.0 / L;
  double td = Tsum * invL;
  double t0 = T0 * invL;
  double wc = WC * invL;

  double tt = td * td;
#pragma unroll
  for (int off = 1; off < 64; off <<= 1) tt += __shfl_xor(tt, off);
  tt -= t0 * t0;

  double mk = tt + wc * wc;
  double un = sqrt(fmax(mk, EPSD));
  double ch = cosh(un), shu = sinh(un) / un;

  double tmd = td + wc * qd;
  double tm0 = t0 + wc * q0;
  double zd = ch * qd + shu * tmd;
  double z0 = ch * q0 + shu * tm0;

  double p2 = zd * zd;
#pragma unroll
  for (int off = 1; off < 64; off <<= 1) p2 += __shfl_xor(p2, off);
  double yn = fmax(sqrt(p2), EPSD);
  double dl = acosh(fmax(z0, 1.0 + EPSD));
  out[wid * 64 + lane] = (float)(dl * zd / yn);
}

// ---------------------------------------------------------------------------
extern "C" void kernel_launch(void* const* d_in, const int* in_sizes, int n_in,
                              void* d_out, int out_size, void* d_ws, size_t ws_size,
                              hipStream_t stream)
{
  const float* queries = (const float*)d_in[0];
  const float* keys    = (const float*)d_in[1];
  const float* values  = (const float*)d_in[2];
  const float* Wq      = (const float*)d_in[3];
  const float* bq      = (const float*)d_in[4];
  const float* Wk      = (const float*)d_in[5];
  const float* bk      = (const float*)d_in[6];
  const float* Wv      = (const float*)d_in[7];
  const float* bv      = (const float*)d_in[8];
  float* out = (float*)d_out;
  float* ws  = (float*)d_ws;

  // slice count chosen by scratch capacity (ws_size constant across calls)
  const size_t base = 1331200;  // floats before Tpart
  int SL = 16;
  {
    size_t need16 = (base + (size_t)16 * 4096 * 64 + 3 * (size_t)16 * 4096) * 4;
    size_t need8  = (base + (size_t)8  * 4096 * 64 + 3 * (size_t)8  * 4096) * 4;
    if (ws_size < need16) SL = (ws_size >= need8) ? 8 : 4;
  }
  const int nChunk = 4096 / SL / 64;  // 4 / 8 / 16

  float* Q0 = ws;                          // 4096
  float* Qr = ws + 4096;                   // 262144
  float* K0 = ws + 266240;                 // 8192
  float* Kr = ws + 274432;                 // 524288
  float* V0 = ws + 798720;                 // 8192
  float* Vr = ws + 806912;                 // 524288
  float* Tpart  = ws + base;               // SL*4096*64
  float* T0part = Tpart + (size_t)SL * 4096 * 64;
  float* Lpart  = T0part + SL * 4096;
  float* WCpart = Lpart + SL * 4096;

  proj_kernel<<<320, 256, 0, stream>>>(queries, keys, values, Wq, bq, Wk, bk,
                                       Wv, bv, Q0, Qr, K0, Kr, V0, Vr);
  attn_kernel<<<dim3(32, SL, 2), 256, 0, stream>>>(
      Q0, Qr, K0, Kr, V0, Vr, Tpart, T0part, Lpart, WCpart, nChunk);
  combine_kernel<<<1024, 256, 0, stream>>>(
      Q0, Qr, Tpart, T0part, Lpart, WCpart, out, SL);
}